// Round 11
// baseline (793.020 us; speedup 1.0000x reference)
//
#include <hip/hip_runtime.h>

typedef __attribute__((ext_vector_type(8))) short bf16x8;
typedef __attribute__((ext_vector_type(4))) float f32x4;
typedef __attribute__((ext_vector_type(4))) unsigned short u16x4;

__device__ __forceinline__ unsigned short f2bf(float f) {
  union { float f; unsigned u; } x; x.f = f;
  unsigned r = x.u + 0x7fffu + ((x.u >> 16) & 1u);
  return (unsigned short)(r >> 16);
}

__device__ __forceinline__ float bf2f(unsigned short u) {
  union { unsigned u; float f; } x; x.u = ((unsigned)u) << 16;
  return x.f;
}

// fp32 -> bf16 convert (b==null) or 0.5*(a+b) blend->bf16, 4 elems/thread
__global__ void k_cvtblend(const float* __restrict__ a, const float* __restrict__ b,
                           unsigned short* __restrict__ o, long n4) {
  long i0 = (long)blockIdx.x * blockDim.x + threadIdx.x;
  long st = (long)gridDim.x * blockDim.x;
  for (long i = i0; i < n4; i += st) {
    f32x4 va = ((const f32x4*)a)[i];
    if (b) {
      f32x4 vb = ((const f32x4*)b)[i];
      va = (va + vb) * 0.5f;
    }
    u16x4 u;
    u[0] = f2bf(va[0]); u[1] = f2bf(va[1]); u[2] = f2bf(va[2]); u[3] = f2bf(va[3]);
    ((u16x4*)o)[i] = u;
  }
}

// one pass: o1 = bf16(a), o2 = bf16(0.5*(a+b))
__global__ void k_cvt2(const float* __restrict__ a, const float* __restrict__ b,
                       unsigned short* __restrict__ o1, unsigned short* __restrict__ o2,
                       long n4) {
  long i0 = (long)blockIdx.x * blockDim.x + threadIdx.x;
  long st = (long)gridDim.x * blockDim.x;
  for (long i = i0; i < n4; i += st) {
    f32x4 va = ((const f32x4*)a)[i];
    f32x4 vb = ((const f32x4*)b)[i];
    u16x4 u1, u2;
    u1[0] = f2bf(va[0]); u1[1] = f2bf(va[1]); u1[2] = f2bf(va[2]); u1[3] = f2bf(va[3]);
    f32x4 vm = (va + vb) * 0.5f;
    u2[0] = f2bf(vm[0]); u2[1] = f2bf(vm[1]); u2[2] = f2bf(vm[2]); u2[3] = f2bf(vm[3]);
    ((u16x4*)o1)[i] = u1;
    ((u16x4*)o2)[i] = u2;
  }
}

// in-place: ab = bf16(0.5*bf2f(ab) + 0.5*bx)   (fallback path)
__global__ void k_blend2(unsigned short* __restrict__ ab, const float* __restrict__ bx, long n4) {
  long i0 = (long)blockIdx.x * blockDim.x + threadIdx.x;
  long st = (long)gridDim.x * blockDim.x;
  for (long i = i0; i < n4; i += st) {
    u16x4 ua = ((u16x4*)ab)[i];
    f32x4 vb = ((const f32x4*)bx)[i];
    u16x4 o;
    o[0] = f2bf(0.5f * bf2f(ua[0]) + 0.5f * vb[0]);
    o[1] = f2bf(0.5f * bf2f(ua[1]) + 0.5f * vb[1]);
    o[2] = f2bf(0.5f * bf2f(ua[2]) + 0.5f * vb[2]);
    o[3] = f2bf(0.5f * bf2f(ua[3]) + 0.5f * vb[3]);
    ((u16x4*)ab)[i] = o;
  }
}

__global__ void k_feat(const float* __restrict__ z, const float* __restrict__ t,
                       unsigned short* __restrict__ o, int realc, int shift,
                       long total, float az, float at) {
  long i0 = (long)blockIdx.x * blockDim.x + threadIdx.x;
  long st = (long)gridDim.x * blockDim.x;
  const int cmask = (1 << shift) - 1;
  for (long i = i0; i < total; i += st) {
    int c = (int)(i & cmask);
    long r = i >> shift;
    float v = 0.f;
    if (c < realc) {
      v = az * z[r * realc + c];
      if (t) v += at * t[r * realc + c];
    }
    o[i] = f2bf(v);
  }
}

__global__ void k_wt(const float* __restrict__ w, unsigned short* __restrict__ o,
                     int K, int N, int kshift, long total) {
  long i0 = (long)blockIdx.x * blockDim.x + threadIdx.x;
  long st = (long)gridDim.x * blockDim.x;
  const int kmask = (1 << kshift) - 1;
  for (long i = i0; i < total; i += st) {
    int k = (int)(i & kmask);
    long n = i >> kshift;
    float v = (n < N && k < K) ? w[(long)k * N + n] : 0.f;
    o[i] = f2bf(v);
  }
}

// plain reduce (L4/L5): S bf16 partial slices -> z fp32 masked, opt relu
__global__ void k_reduce(const unsigned short* __restrict__ part, float* __restrict__ z,
                         int S, int ldp, int n4shift, int nreal, int relu, long total4) {
  long i0 = (long)blockIdx.x * blockDim.x + threadIdx.x;
  long st = (long)gridDim.x * blockDim.x;
  const int n4mask = (1 << n4shift) - 1;
  for (long i = i0; i < total4; i += st) {
    long m = i >> n4shift;
    int n4 = (int)(i & n4mask);
    float v0 = 0.f, v1 = 0.f, v2 = 0.f, v3 = 0.f;
    for (int s = 0; s < S; ++s) {
      u16x4 u = *(const u16x4*)(part + (size_t)s * 8192 * ldp + m * ldp + n4 * 4);
      v0 += bf2f(u[0]); v1 += bf2f(u[1]); v2 += bf2f(u[2]); v3 += bf2f(u[3]);
    }
    if (relu) {
      v0 = fmaxf(v0, 0.f); v1 = fmaxf(v1, 0.f);
      v2 = fmaxf(v2, 0.f); v3 = fmaxf(v3, 0.f);
    }
    int c0 = n4 * 4;
    float* zr = z + m * nreal;
    if (c0 + 3 < nreal) {
      zr[c0] = v0; zr[c0 + 1] = v1; zr[c0 + 2] = v2; zr[c0 + 3] = v3;
    } else {
      if (c0 < nreal) zr[c0] = v0;
      if (c0 + 1 < nreal) zr[c0 + 1] = v1;
      if (c0 + 2 < nreal) zr[c0 + 2] = v2;
      if (c0 + 3 < nreal) zr[c0 + 3] = v3;
    }
  }
}

// fused reduce: z = relu(sum(part)); feat = bf16(0.5*z + 0.5*tra) padded to ldp.
__global__ void k_reduce_f(const unsigned short* __restrict__ part, float* __restrict__ z,
                           const float* __restrict__ tra, unsigned short* __restrict__ feat,
                           int S, int ldp, int n4shift, int nreal, long total4) {
  long i0 = (long)blockIdx.x * blockDim.x + threadIdx.x;
  long st = (long)gridDim.x * blockDim.x;
  const int n4mask = (1 << n4shift) - 1;
  for (long i = i0; i < total4; i += st) {
    long m = i >> n4shift;
    int n4 = (int)(i & n4mask);
    float v[4] = {0.f, 0.f, 0.f, 0.f};
    for (int s = 0; s < S; ++s) {
      u16x4 u = *(const u16x4*)(part + (size_t)s * 8192 * ldp + m * ldp + n4 * 4);
      v[0] += bf2f(u[0]); v[1] += bf2f(u[1]); v[2] += bf2f(u[2]); v[3] += bf2f(u[3]);
    }
    const int c0 = n4 * 4;
    float* zr = z + m * nreal;
    u16x4 fo;
#pragma unroll
    for (int j = 0; j < 4; ++j) {
      const int c = c0 + j;
      float vr = fmaxf(v[j], 0.f);
      float f = 0.f;
      if (c < nreal) {
        zr[c] = vr;
        f = 0.5f * vr + 0.5f * tra[m * nreal + c];
      }
      fo[j] = f2bf(f);
    }
    *(u16x4*)(feat + m * ldp + c0) = fo;
  }
}

// ---------------- 128x128 4-wave kernel (proven; used for small GEMMs) -------
template<int EPI>
__global__ __launch_bounds__(256)
void k_gemm(const unsigned short* __restrict__ A, const unsigned short* __restrict__ BT,
            float* __restrict__ C, unsigned short* __restrict__ CT,
            int K, int Kc, int ldc, int nreal) {
  __shared__ unsigned short As[128 * 64];
  __shared__ unsigned short Bs[128 * 64];
  const int tid = threadIdx.x;
  const int wv = tid >> 6, ln = tid & 63;
  const int m0 = blockIdx.x << 7;
  const int n0 = blockIdx.y << 7;
  const int sidx = blockIdx.z;
  const int wrow = (wv >> 1) << 6;
  const int wcol = (wv & 1) << 6;
  const int lrow = ln & 15;
  const int khalf = ln >> 4;
  const int r3 = lrow & 7;

  const f32x4 zero = {0.f, 0.f, 0.f, 0.f};
  f32x4 acc[4][4];
#pragma unroll
  for (int m = 0; m < 4; ++m)
#pragma unroll
    for (int n = 0; n < 4; ++n) acc[m][n] = zero;

  const int crow = ln >> 3;
  const int ssl = (ln & 7) ^ crow;

  const int klo = sidx * Kc;
  const int khi = klo + Kc;

  for (int kk = klo; kk < khi; kk += 64) {
#pragma unroll
    for (int c = 0; c < 4; ++c) {
      const int ch = wv * 4 + c;
      const int row = ch * 8 + crow;
      __builtin_amdgcn_global_load_lds(
          (const __attribute__((address_space(1))) void*)(A + (size_t)(m0 + row) * K + kk + ssl * 8),
          (__attribute__((address_space(3))) void*)(As + ch * 512), 16, 0, 0);
      __builtin_amdgcn_global_load_lds(
          (const __attribute__((address_space(1))) void*)(BT + (size_t)(n0 + row) * K + kk + ssl * 8),
          (__attribute__((address_space(3))) void*)(Bs + ch * 512), 16, 0, 0);
    }
    __syncthreads();

#pragma unroll
    for (int kb = 0; kb < 2; ++kb) {
      const int sl = ((kb << 2) | khalf) ^ r3;
      bf16x8 af[4], bfr[4];
#pragma unroll
      for (int m = 0; m < 4; ++m)
        af[m] = *(const bf16x8*)(As + (wrow + m * 16 + lrow) * 64 + sl * 8);
#pragma unroll
      for (int n = 0; n < 4; ++n)
        bfr[n] = *(const bf16x8*)(Bs + (wcol + n * 16 + lrow) * 64 + sl * 8);
#pragma unroll
      for (int m = 0; m < 4; ++m)
#pragma unroll
        for (int n = 0; n < 4; ++n)
          acc[m][n] = __builtin_amdgcn_mfma_f32_16x16x32_bf16(af[m], bfr[n], acc[m][n], 0, 0, 0);
    }
    __syncthreads();
  }

  const int rbase = khalf << 2;
  if (EPI == 2) {
#pragma unroll
    for (int n = 0; n < 4; ++n) {
      const size_t col = (size_t)(n0 + wcol + n * 16 + lrow);
#pragma unroll
      for (int m = 0; m < 4; ++m) {
        const size_t row = (size_t)(m0 + wrow + m * 16 + rbase);
        u16x4 pk;
        pk[0] = f2bf(acc[m][n][0]); pk[1] = f2bf(acc[m][n][1]);
        pk[2] = f2bf(acc[m][n][2]); pk[3] = f2bf(acc[m][n][3]);
        *(u16x4*)(CT + col * 8192 + row) = pk;
      }
    }
  } else if (EPI == 3) {
    const size_t pbase = (size_t)sidx * 8192 * ldc;
#pragma unroll
    for (int n = 0; n < 4; ++n) {
      const int col = n0 + wcol + n * 16 + lrow;
#pragma unroll
      for (int m = 0; m < 4; ++m) {
        const size_t row = (size_t)(m0 + wrow + m * 16 + rbase);
#pragma unroll
        for (int j = 0; j < 4; ++j)
          CT[pbase + (row + j) * ldc + col] = f2bf(acc[m][n][j]);
      }
    }
  } else {
#pragma unroll
    for (int n = 0; n < 4; ++n) {
      const int col = n0 + wcol + n * 16 + lrow;
      if (col < nreal) {
#pragma unroll
        for (int m = 0; m < 4; ++m) {
          const size_t row = (size_t)(m0 + wrow + m * 16 + rbase);
          float v0 = acc[m][n][0], v1 = acc[m][n][1];
          float v2 = acc[m][n][2], v3 = acc[m][n][3];
          if (EPI == 0) {
            v0 = fmaxf(v0, 0.f); v1 = fmaxf(v1, 0.f);
            v2 = fmaxf(v2, 0.f); v3 = fmaxf(v3, 0.f);
          }
          C[(row + 0) * ldc + col] = v0;
          C[(row + 1) * ldc + col] = v1;
          C[(row + 2) * ldc + col] = v2;
          C[(row + 3) * ldc + col] = v3;
        }
      }
    }
  }
}

// ---------------- 256x256 8-wave 8-phase kernel ------------------------------
// Round-5 dedup schedule; ds_reads moved AFTER barrier-1 into the SAME
// scheduling region as the MFMA bundle (no sched_barrier between them) so the
// compiler emits counted lgkmcnt waits and overlaps LDS reads with MFMA.
// Stage issue order, vmcnt ledger (VMC@ph4, VM4@ph8) and barriers unchanged.
// Hazards re-verified: every read completes before its first consuming MFMA
// (same phase); every region overwrite issues >=2 barriers after the last
// read's consuming phase; same-phase stage/read regions are disjoint.
__device__ __forceinline__ void stage_unit(
    const unsigned short* __restrict__ G, int g0, int Kst, int kk,
    char* lds_tile, int isB, int h, int wv, int ln) {
#pragma unroll
  for (int i = 0; i < 2; ++i) {
    const int c = wv * 2 + i;
    int rb;
    if (isB) rb = ((c >> 2) << 6) + h * 32 + ((c & 3) << 3);
    else     rb = ((c & 8) << 4) + h * 64 + ((c & 7) << 3);
    const int ssl = (ln & 7) ^ (ln >> 3);
    const unsigned short* src = G + (size_t)(g0 + rb + (ln >> 3)) * Kst + kk + ssl * 8;
    __builtin_amdgcn_global_load_lds(
        (const __attribute__((address_space(1))) void*)src,
        (__attribute__((address_space(3))) void*)(lds_tile + rb * 128), 16, 0, 0);
  }
}

#define VM_NONE
#define VM4 asm volatile("s_waitcnt vmcnt(4)" ::: "memory");
#define VM0 asm volatile("s_waitcnt vmcnt(0)" ::: "memory");
#define VMC if (more) { VM4 } else { VM0 }

#define LD_FA(BB, MH)                                                              \
  _Pragma("unroll") for (int kb = 0; kb < 2; ++kb) {                               \
    const int sl = ((kb << 2) | khalf) ^ r3;                                       \
    _Pragma("unroll") for (int fr = 0; fr < 4; ++fr)                               \
      fa[fr][kb] = *(const bf16x8*)((const unsigned short*)(smem + (BB) * 65536)   \
                   + (wmrow + (MH) * 64 + fr * 16 + lrow) * 64 + sl * 8);          \
  }

#define LD_FB(BB, NH, F)                                                           \
  _Pragma("unroll") for (int kb = 0; kb < 2; ++kb) {                               \
    const int sl = ((kb << 2) | khalf) ^ r3;                                       \
    _Pragma("unroll") for (int fc = 0; fc < 2; ++fc)                               \
      F[fc][kb] = *(const bf16x8*)((const unsigned short*)(smem + (BB) * 65536 + 32768) \
                  + (wncol + (NH) * 32 + fc * 16 + lrow) * 64 + sl * 8);           \
  }

#define PH(MH, NH, F, WAITSTMT, DSSTMT, ...)                                       \
  {                                                                                \
    __VA_ARGS__;                                                                   \
    __builtin_amdgcn_sched_barrier(0);                                             \
    __builtin_amdgcn_s_barrier();                                                  \
    __builtin_amdgcn_sched_barrier(0);                                             \
    __builtin_amdgcn_s_setprio(1);                                                 \
    DSSTMT                                                                         \
    _Pragma("unroll") for (int kb = 0; kb < 2; ++kb)                               \
      _Pragma("unroll") for (int fr = 0; fr < 4; ++fr)                             \
        _Pragma("unroll") for (int fc = 0; fc < 2; ++fc)                           \
          acc[MH][NH][fr][fc] = __builtin_amdgcn_mfma_f32_16x16x32_bf16(           \
              fa[fr][kb], F[fc][kb], acc[MH][NH][fr][fc], 0, 0, 0);                \
    __builtin_amdgcn_s_setprio(0);                                                 \
    __builtin_amdgcn_sched_barrier(0);                                             \
    WAITSTMT                                                                       \
    __builtin_amdgcn_s_barrier();                                                  \
    __builtin_amdgcn_sched_barrier(0);                                             \
  }

template<int EPI>
__global__ __launch_bounds__(512, 1)
void k_gemm256(const unsigned short* __restrict__ A, const unsigned short* __restrict__ BT,
               float* __restrict__ C, unsigned short* __restrict__ CT,
               int K, int Kc, int ldc, int nreal) {
  extern __shared__ char smem[];
  const int tid = threadIdx.x;
  const int wv = tid >> 6, ln = tid & 63;
  const int wmrow = (wv >> 2) << 7;
  const int wncol = (wv & 3) << 6;
  const int lrow = ln & 15, khalf = ln >> 4, r3 = ln & 7;

  // XCD-aware bijective swizzle, n-major within each XCD's chunk.
  const int gx = gridDim.x, gy = gridDim.y;
  const int nwg = gx * gy;
  const int bid = blockIdx.y * gx + blockIdx.x;
  const int q8 = nwg >> 3, r8 = nwg & 7;
  const int xcd = bid & 7, lx = bid >> 3;
  const int wgid = (xcd < r8 ? xcd * (q8 + 1) : r8 * (q8 + 1) + (xcd - r8) * q8) + lx;
  const int m0 = (wgid / gy) << 8;
  const int n0 = (wgid % gy) << 8;
  const int klo = blockIdx.z * Kc;
  const int NT = Kc >> 6;
  const int npairs = NT >> 1;

  f32x4 acc[2][2][4][2];
#pragma unroll
  for (int a0 = 0; a0 < 2; ++a0)
#pragma unroll
    for (int a1 = 0; a1 < 2; ++a1)
#pragma unroll
      for (int a2 = 0; a2 < 4; ++a2)
#pragma unroll
        for (int a3 = 0; a3 < 2; ++a3) {
          acc[a0][a1][a2][a3][0] = 0.f; acc[a0][a1][a2][a3][1] = 0.f;
          acc[a0][a1][a2][a3][2] = 0.f; acc[a0][a1][a2][a3][3] = 0.f;
        }

  bf16x8 fa[4][2], fb0[2][2], fb1[2][2];

  stage_unit(A, m0, K, klo, smem, 0, 0, wv, ln);
  stage_unit(BT, n0, K, klo, smem + 32768, 1, 0, wv, ln);
  stage_unit(BT, n0, K, klo, smem + 32768, 1, 1, wv, ln);
  stage_unit(A, m0, K, klo, smem, 0, 1, wv, ln);
  stage_unit(A, m0, K, klo + 64, smem + 65536, 0, 0, wv, ln);
  stage_unit(BT, n0, K, klo + 64, smem + 65536 + 32768, 1, 0, wv, ln);
  VM4
  __builtin_amdgcn_sched_barrier(0);
  __builtin_amdgcn_s_barrier();
  __builtin_amdgcn_sched_barrier(0);

  for (int i = 0; i < npairs; ++i) {
    const int t = i << 1;
    const int kk1 = klo + (t + 1) * 64;
    const int kk2 = klo + (t + 2) * 64;
    const int kk3 = klo + (t + 3) * 64;
    const bool more = (i + 1 < npairs);

    PH(0, 0, fb0, VM_NONE, LD_FA(0, 0) LD_FB(0, 0, fb0),
       stage_unit(A, m0, K, kk1, smem + 65536, 0, 1, wv, ln))
    PH(0, 1, fb1, VM_NONE, LD_FB(0, 1, fb1),
       stage_unit(BT, n0, K, kk1, smem + 65536 + 32768, 1, 1, wv, ln))
    PH(1, 0, fb0, VM_NONE, LD_FA(0, 1),
       if (more) stage_unit(A, m0, K, kk2, smem, 0, 0, wv, ln))
    PH(1, 1, fb1, VMC, ,
       if (more) stage_unit(BT, n0, K, kk2, smem + 32768, 1, 0, wv, ln))
    PH(0, 0, fb0, VM_NONE, LD_FA(1, 0) LD_FB(1, 0, fb0),
       if (more) stage_unit(A, m0, K, kk2, smem, 0, 1, wv, ln))
    PH(0, 1, fb1, VM_NONE, LD_FB(1, 1, fb1),
       if (more) stage_unit(BT, n0, K, kk2, smem + 32768, 1, 1, wv, ln))
    PH(1, 0, fb0, VM_NONE, LD_FA(1, 1),
       if (more) stage_unit(A, m0, K, kk3, smem + 65536, 0, 0, wv, ln))
    PH(1, 1, fb1, if (more) { VM4 }, ,
       if (more) stage_unit(BT, n0, K, kk3, smem + 65536 + 32768, 1, 0, wv, ln))
  }

  const int rb = khalf << 2;
  if (EPI == 2) {
#pragma unroll
    for (int mh = 0; mh < 2; ++mh)
#pragma unroll
      for (int nh = 0; nh < 2; ++nh)
#pragma unroll
        for (int fr = 0; fr < 4; ++fr)
#pragma unroll
          for (int fc = 0; fc < 2; ++fc) {
            const size_t col = (size_t)(n0 + wncol + nh * 32 + fc * 16 + lrow);
            const size_t row = (size_t)(m0 + wmrow + mh * 64 + fr * 16 + rb);
            u16x4 pk;
            pk[0] = f2bf(acc[mh][nh][fr][fc][0]); pk[1] = f2bf(acc[mh][nh][fr][fc][1]);
            pk[2] = f2bf(acc[mh][nh][fr][fc][2]); pk[3] = f2bf(acc[mh][nh][fr][fc][3]);
            *(u16x4*)(CT + col * 8192 + row) = pk;
          }
  } else if (EPI == 3) {
    const size_t pbase = (size_t)blockIdx.z * 8192 * ldc;
#pragma unroll
    for (int mh = 0; mh < 2; ++mh)
#pragma unroll
      for (int nh = 0; nh < 2; ++nh)
#pragma unroll
        for (int fr = 0; fr < 4; ++fr)
#pragma unroll
          for (int fc = 0; fc < 2; ++fc) {
            const int col = n0 + wncol + nh * 32 + fc * 16 + lrow;
            const size_t row = (size_t)(m0 + wmrow + mh * 64 + fr * 16 + rb);
#pragma unroll
            for (int j = 0; j < 4; ++j)
              CT[pbase + (row + j) * ldc + col] = f2bf(acc[mh][nh][fr][fc][j]);
          }
  } else {
#pragma unroll
    for (int mh = 0; mh < 2; ++mh)
#pragma unroll
      for (int nh = 0; nh < 2; ++nh)
#pragma unroll
        for (int fc = 0; fc < 2; ++fc) {
          const int col = n0 + wncol + nh * 32 + fc * 16 + lrow;
          if (col < nreal) {
#pragma unroll
            for (int fr = 0; fr < 4; ++fr) {
              const size_t row = (size_t)(m0 + wmrow + mh * 64 + fr * 16 + rb);
#pragma unroll
              for (int j = 0; j < 4; ++j) {
                float v = acc[mh][nh][fr][fc][j];
                if (EPI == 0) v = fmaxf(v, 0.f);
                C[(row + j) * ldc + col] = v;
              }
            }
          }
        }
  }
}

extern "C" void kernel_launch(void* const* d_in, const int* in_sizes, int n_in,
                              void* d_out, int out_size, void* d_ws, size_t ws_size,
                              hipStream_t stream) {
  (void)in_sizes; (void)n_in; (void)out_size;
  const float* x    = (const float*)d_in[0];
  const float* adj  = (const float*)d_in[1];
  const float* adjx = (const float*)d_in[2];
  const float* tra1 = (const float*)d_in[3];
  const float* tra2 = (const float*)d_in[4];
  const float* tra3 = (const float*)d_in[5];
  const float* h    = (const float*)d_in[6];
  const float* W1   = (const float*)d_in[7];
  const float* W2   = (const float*)d_in[8];
  const float* W3   = (const float*)d_in[9];
  const float* W4   = (const float*)d_in[10];
  const float* W5   = (const float*)d_in[11];
  float* out = (float*)d_out;

  const size_t ADJ_B  = 134217728;
  const size_t FEAT_B = 33554432;
  const size_t SUP_B  = 33554432;
  const size_t W_B    = 2097152;
  if (ws_size < ADJ_B + FEAT_B + SUP_B + W_B) return;
  const bool twoadj = ws_size >= 2 * ADJ_B + FEAT_B + SUP_B + W_B;
  char* ws = (char*)d_ws;
  unsigned short* adjB = (unsigned short*)ws;
  unsigned short* adjW;   // blended adjacency (layers 2-5)
  unsigned short *featB, *supB, *wB;
  if (twoadj) {
    adjW  = (unsigned short*)(ws + ADJ_B);
    featB = (unsigned short*)(ws + 2 * ADJ_B);
    supB  = (unsigned short*)(ws + 2 * ADJ_B + FEAT_B);
    wB    = (unsigned short*)(ws + 2 * ADJ_B + FEAT_B + SUP_B);
  } else {
    adjW  = adjB;
    featB = (unsigned short*)(ws + ADJ_B);
    supB  = (unsigned short*)(ws + ADJ_B + FEAT_B);
    wB    = (unsigned short*)(ws + ADJ_B + FEAT_B + SUP_B);
  }
  unsigned short* partB = featB;

  float* z5 = out;
  float* z1 = out + 81920;
  float* z2 = out + 4177920;
  float* z3 = out + 8273920;
  float* z4 = out + 24657920;

  const long n4adj = (long)8192 * 8192 / 4;
  const int SMEM = 131072;

  bool big = true;
  if (hipFuncSetAttribute(reinterpret_cast<const void*>(&k_gemm256<0>),
                          hipFuncAttributeMaxDynamicSharedMemorySize, SMEM) != hipSuccess) big = false;
  if (hipFuncSetAttribute(reinterpret_cast<const void*>(&k_gemm256<2>),
                          hipFuncAttributeMaxDynamicSharedMemorySize, SMEM) != hipSuccess) big = false;
  if (hipFuncSetAttribute(reinterpret_cast<const void*>(&k_gemm256<3>),
                          hipFuncAttributeMaxDynamicSharedMemorySize, SMEM) != hipSuccess) big = false;

  // ---- layer 1 ----
  if (twoadj)
    k_cvt2<<<2048, 256, 0, stream>>>(adj, adjx, adjB, adjW, n4adj);
  else
    k_cvtblend<<<2048, 256, 0, stream>>>(adj, nullptr, adjB, n4adj);
  k_feat<<<2048, 256, 0, stream>>>(x, nullptr, featB, 1000, 10, (long)8192 * 1024, 1.f, 0.f);
  k_wt<<<512, 256, 0, stream>>>(W1, wB, 1000, 500, 10, (long)512 * 1024);
  k_gemm<2><<<dim3(64, 4, 1), 256, 0, stream>>>(featB, wB, nullptr, supB, 1024, 1024, 0, 0);
  if (big)
    k_gemm256<3><<<dim3(32, 2, 4), 512, SMEM, stream>>>(adjB, supB, nullptr, partB, 8192, 2048, 512, 0);
  else
    k_gemm<3><<<dim3(64, 4, 4), 256, 0, stream>>>(adjB, supB, nullptr, partB, 8192, 2048, 512, 0);
  // fused: z1 + feat2 (feat2 overwrites part slice-0 region, alias-safe)
  k_reduce_f<<<2048, 256, 0, stream>>>(partB, z1, tra1, featB, 4, 512, 7, 500, (long)8192 * 128);

  if (!twoadj)
    k_blend2<<<2048, 256, 0, stream>>>(adjB, adjx, n4adj);

  // ---- layer 2 ----
  k_wt<<<512, 256, 0, stream>>>(W2, wB, 500, 500, 9, (long)512 * 512);
  k_gemm<2><<<dim3(64, 4, 1), 256, 0, stream>>>(featB, wB, nullptr, supB, 512, 512, 0, 0);
  if (big)
    k_gemm256<3><<<dim3(32, 2, 4), 512, SMEM, stream>>>(adjW, supB, nullptr, partB, 8192, 2048, 512, 0);
  else
    k_gemm<3><<<dim3(64, 4, 4), 256, 0, stream>>>(adjW, supB, nullptr, partB, 8192, 2048, 512, 0);
  // fused: z2 + feat3
  k_reduce_f<<<2048, 256, 0, stream>>>(partB, z2, tra2, featB, 4, 512, 7, 500, (long)8192 * 128);

  // ---- layer 3 ----
  k_wt<<<512, 256, 0, stream>>>(W3, wB, 500, 2000, 9, (long)2048 * 512);
  if (big) {
    k_gemm256<2><<<dim3(32, 8, 1), 512, SMEM, stream>>>(featB, wB, nullptr, supB, 512, 512, 0, 0);
    k_gemm256<0><<<dim3(32, 8, 1), 512, SMEM, stream>>>(adjW, supB, z3, nullptr, 8192, 8192, 2000, 2000);
  } else {
    k_gemm<2><<<dim3(64, 16, 1), 256, 0, stream>>>(featB, wB, nullptr, supB, 512, 512, 0, 0);
    k_gemm<0><<<dim3(64, 16, 1), 256, 0, stream>>>(adjW, supB, z3, nullptr, 8192, 8192, 2000, 2000);
  }
  k_feat<<<2048, 256, 0, stream>>>(z3, tra3, featB, 2000, 11, (long)8192 * 2048, 0.5f, 0.5f);

  // ---- layer 4 (round-5 proven split-K path) ----
  k_wt<<<512, 256, 0, stream>>>(W4, wB, 2000, 10, 11, (long)128 * 2048);
  k_gemm<2><<<dim3(64, 1, 1), 256, 0, stream>>>(featB, wB, nullptr, supB, 2048, 2048, 0, 0);
  k_gemm<3><<<dim3(64, 1, 8), 256, 0, stream>>>(adjW, supB, nullptr, partB, 8192, 1024, 128, 0);
  k_reduce<<<2048, 256, 0, stream>>>(partB, z4, 8, 128, 5, 10, 1, (long)8192 * 32);

  // ---- layer 5 (no relu) ----
  k_feat<<<512, 256, 0, stream>>>(z4, h, featB, 10, 6, (long)8192 * 64, 0.5f, 0.5f);
  k_wt<<<64, 256, 0, stream>>>(W5, wB, 10, 10, 6, (long)128 * 64);
  k_gemm<2><<<dim3(64, 1, 1), 256, 0, stream>>>(featB, wB, nullptr, supB, 64, 64, 0, 0);
  k_gemm<3><<<dim3(64, 1, 8), 256, 0, stream>>>(adjW, supB, nullptr, partB, 8192, 1024, 128, 0);
  k_reduce<<<2048, 256, 0, stream>>>(partB, z5, 8, 128, 5, 10, 0, (long)8192 * 32);
}

// Round 12
// 659.969 us; speedup vs baseline: 1.2016x; 1.2016x over previous
//
#include <hip/hip_runtime.h>

typedef __attribute__((ext_vector_type(8))) short bf16x8;
typedef __attribute__((ext_vector_type(4))) float f32x4;
typedef __attribute__((ext_vector_type(4))) unsigned short u16x4;

__device__ __forceinline__ unsigned short f2bf(float f) {
  union { float f; unsigned u; } x; x.f = f;
  unsigned r = x.u + 0x7fffu + ((x.u >> 16) & 1u);
  return (unsigned short)(r >> 16);
}

__device__ __forceinline__ float bf2f(unsigned short u) {
  union { unsigned u; float f; } x; x.u = ((unsigned)u) << 16;
  return x.f;
}

// fp32 -> bf16 convert (b==null) or 0.5*(a+b) blend->bf16, 4 elems/thread
__global__ void k_cvtblend(const float* __restrict__ a, const float* __restrict__ b,
                           unsigned short* __restrict__ o, long n4) {
  long i0 = (long)blockIdx.x * blockDim.x + threadIdx.x;
  long st = (long)gridDim.x * blockDim.x;
  for (long i = i0; i < n4; i += st) {
    f32x4 va = ((const f32x4*)a)[i];
    if (b) {
      f32x4 vb = ((const f32x4*)b)[i];
      va = (va + vb) * 0.5f;
    }
    u16x4 u;
    u[0] = f2bf(va[0]); u[1] = f2bf(va[1]); u[2] = f2bf(va[2]); u[3] = f2bf(va[3]);
    ((u16x4*)o)[i] = u;
  }
}

// one pass: o1 = bf16(a), o2 = bf16(0.5*(a+b))
__global__ void k_cvt2(const float* __restrict__ a, const float* __restrict__ b,
                       unsigned short* __restrict__ o1, unsigned short* __restrict__ o2,
                       long n4) {
  long i0 = (long)blockIdx.x * blockDim.x + threadIdx.x;
  long st = (long)gridDim.x * blockDim.x;
  for (long i = i0; i < n4; i += st) {
    f32x4 va = ((const f32x4*)a)[i];
    f32x4 vb = ((const f32x4*)b)[i];
    u16x4 u1, u2;
    u1[0] = f2bf(va[0]); u1[1] = f2bf(va[1]); u1[2] = f2bf(va[2]); u1[3] = f2bf(va[3]);
    f32x4 vm = (va + vb) * 0.5f;
    u2[0] = f2bf(vm[0]); u2[1] = f2bf(vm[1]); u2[2] = f2bf(vm[2]); u2[3] = f2bf(vm[3]);
    ((u16x4*)o1)[i] = u1;
    ((u16x4*)o2)[i] = u2;
  }
}

// in-place: ab = bf16(0.5*bf2f(ab) + 0.5*bx)   (fallback path)
__global__ void k_blend2(unsigned short* __restrict__ ab, const float* __restrict__ bx, long n4) {
  long i0 = (long)blockIdx.x * blockDim.x + threadIdx.x;
  long st = (long)gridDim.x * blockDim.x;
  for (long i = i0; i < n4; i += st) {
    u16x4 ua = ((u16x4*)ab)[i];
    f32x4 vb = ((const f32x4*)bx)[i];
    u16x4 o;
    o[0] = f2bf(0.5f * bf2f(ua[0]) + 0.5f * vb[0]);
    o[1] = f2bf(0.5f * bf2f(ua[1]) + 0.5f * vb[1]);
    o[2] = f2bf(0.5f * bf2f(ua[2]) + 0.5f * vb[2]);
    o[3] = f2bf(0.5f * bf2f(ua[3]) + 0.5f * vb[3]);
    ((u16x4*)ab)[i] = o;
  }
}

__global__ void k_feat(const float* __restrict__ z, const float* __restrict__ t,
                       unsigned short* __restrict__ o, int realc, int shift,
                       long total, float az, float at) {
  long i0 = (long)blockIdx.x * blockDim.x + threadIdx.x;
  long st = (long)gridDim.x * blockDim.x;
  const int cmask = (1 << shift) - 1;
  for (long i = i0; i < total; i += st) {
    int c = (int)(i & cmask);
    long r = i >> shift;
    float v = 0.f;
    if (c < realc) {
      v = az * z[r * realc + c];
      if (t) v += at * t[r * realc + c];
    }
    o[i] = f2bf(v);
  }
}

__global__ void k_wt(const float* __restrict__ w, unsigned short* __restrict__ o,
                     int K, int N, int kshift, long total) {
  long i0 = (long)blockIdx.x * blockDim.x + threadIdx.x;
  long st = (long)gridDim.x * blockDim.x;
  const int kmask = (1 << kshift) - 1;
  for (long i = i0; i < total; i += st) {
    int k = (int)(i & kmask);
    long n = i >> kshift;
    float v = (n < N && k < K) ? w[(long)k * N + n] : 0.f;
    o[i] = f2bf(v);
  }
}

// bf16 [R][Cc] -> bf16 [Cc][R] transpose, 64x64 LDS tiles
__global__ __launch_bounds__(256)
void k_tr(const unsigned short* __restrict__ in, unsigned short* __restrict__ out,
          int R, int Cc) {
  __shared__ unsigned short ts[64][65];
  const int tid = threadIdx.x;
  const int m0 = blockIdx.x * 64;
  const int c0 = blockIdx.y * 64;
  const int rr = tid >> 3;
  const int eb = (tid & 7) * 8;
#pragma unroll
  for (int j = 0; j < 2; ++j) {
    const int r = j * 32 + rr;
    const unsigned short* src = in + (size_t)(m0 + r) * Cc + c0 + eb;
    u16x4 v0 = *(const u16x4*)src;
    u16x4 v1 = *(const u16x4*)(src + 4);
#pragma unroll
    for (int q = 0; q < 4; ++q) { ts[r][eb + q] = v0[q]; ts[r][eb + 4 + q] = v1[q]; }
  }
  __syncthreads();
#pragma unroll
  for (int j = 0; j < 2; ++j) {
    const int c = j * 32 + rr;
    u16x4 o0, o1;
#pragma unroll
    for (int q = 0; q < 4; ++q) { o0[q] = ts[eb + q][c]; o1[q] = ts[eb + 4 + q][c]; }
    unsigned short* dst = out + (size_t)(c0 + c) * R + m0 + eb;
    *(u16x4*)dst = o0;
    *(u16x4*)(dst + 4) = o1;
  }
}

// plain reduce (L4/L5): S bf16 partial slices -> z fp32 masked, opt relu
__global__ void k_reduce(const unsigned short* __restrict__ part, float* __restrict__ z,
                         int S, int ldp, int n4shift, int nreal, int relu, long total4) {
  long i0 = (long)blockIdx.x * blockDim.x + threadIdx.x;
  long st = (long)gridDim.x * blockDim.x;
  const int n4mask = (1 << n4shift) - 1;
  for (long i = i0; i < total4; i += st) {
    long m = i >> n4shift;
    int n4 = (int)(i & n4mask);
    float v0 = 0.f, v1 = 0.f, v2 = 0.f, v3 = 0.f;
    for (int s = 0; s < S; ++s) {
      u16x4 u = *(const u16x4*)(part + (size_t)s * 8192 * ldp + m * ldp + n4 * 4);
      v0 += bf2f(u[0]); v1 += bf2f(u[1]); v2 += bf2f(u[2]); v3 += bf2f(u[3]);
    }
    if (relu) {
      v0 = fmaxf(v0, 0.f); v1 = fmaxf(v1, 0.f);
      v2 = fmaxf(v2, 0.f); v3 = fmaxf(v3, 0.f);
    }
    int c0 = n4 * 4;
    float* zr = z + m * nreal;
    if (c0 + 3 < nreal) {
      zr[c0] = v0; zr[c0 + 1] = v1; zr[c0 + 2] = v2; zr[c0 + 3] = v3;
    } else {
      if (c0 < nreal) zr[c0] = v0;
      if (c0 + 1 < nreal) zr[c0 + 1] = v1;
      if (c0 + 2 < nreal) zr[c0 + 2] = v2;
      if (c0 + 3 < nreal) zr[c0 + 3] = v3;
    }
  }
}

// fused reduce: z = relu(sum(part)); feat = bf16(0.5*z + 0.5*tra) padded to ldp.
__global__ void k_reduce_f(const unsigned short* __restrict__ part, float* __restrict__ z,
                           const float* __restrict__ tra, unsigned short* __restrict__ feat,
                           int S, int ldp, int n4shift, int nreal, long total4) {
  long i0 = (long)blockIdx.x * blockDim.x + threadIdx.x;
  long st = (long)gridDim.x * blockDim.x;
  const int n4mask = (1 << n4shift) - 1;
  for (long i = i0; i < total4; i += st) {
    long m = i >> n4shift;
    int n4 = (int)(i & n4mask);
    float v[4] = {0.f, 0.f, 0.f, 0.f};
    for (int s = 0; s < S; ++s) {
      u16x4 u = *(const u16x4*)(part + (size_t)s * 8192 * ldp + m * ldp + n4 * 4);
      v[0] += bf2f(u[0]); v[1] += bf2f(u[1]); v[2] += bf2f(u[2]); v[3] += bf2f(u[3]);
    }
    const int c0 = n4 * 4;
    float* zr = z + m * nreal;
    u16x4 fo;
#pragma unroll
    for (int j = 0; j < 4; ++j) {
      const int c = c0 + j;
      float vr = fmaxf(v[j], 0.f);
      float f = 0.f;
      if (c < nreal) {
        zr[c] = vr;
        f = 0.5f * vr + 0.5f * tra[m * nreal + c];
      }
      fo[j] = f2bf(f);
    }
    *(u16x4*)(feat + m * ldp + c0) = fo;
  }
}

// sum S partial slices -> bf16 (no relu, no mask); o aliases slice 0 (identity map)
__global__ void k_reduce_b(const unsigned short* __restrict__ part, unsigned short* __restrict__ o,
                           int S, long ldtot, long total4) {
  long i0 = (long)blockIdx.x * blockDim.x + threadIdx.x;
  long st = (long)gridDim.x * blockDim.x;
  for (long i = i0; i < total4; i += st) {
    float v[4] = {0.f, 0.f, 0.f, 0.f};
    for (int s = 0; s < S; ++s) {
      u16x4 u = *(const u16x4*)(part + s * ldtot + i * 4);
      v[0] += bf2f(u[0]); v[1] += bf2f(u[1]); v[2] += bf2f(u[2]); v[3] += bf2f(u[3]);
    }
    u16x4 w;
    w[0] = f2bf(v[0]); w[1] = f2bf(v[1]); w[2] = f2bf(v[2]); w[3] = f2bf(v[3]);
    *(u16x4*)(o + i * 4) = w;
  }
}

// ---------------- 128x128 4-wave kernel (proven; used for small GEMMs) -------
template<int EPI>
__global__ __launch_bounds__(256)
void k_gemm(const unsigned short* __restrict__ A, const unsigned short* __restrict__ BT,
            float* __restrict__ C, unsigned short* __restrict__ CT,
            int K, int Kc, int ldc, int nreal) {
  __shared__ unsigned short As[128 * 64];
  __shared__ unsigned short Bs[128 * 64];
  const int tid = threadIdx.x;
  const int wv = tid >> 6, ln = tid & 63;
  const int m0 = blockIdx.x << 7;
  const int n0 = blockIdx.y << 7;
  const int sidx = blockIdx.z;
  const int wrow = (wv >> 1) << 6;
  const int wcol = (wv & 1) << 6;
  const int lrow = ln & 15;
  const int khalf = ln >> 4;
  const int r3 = lrow & 7;

  const f32x4 zero = {0.f, 0.f, 0.f, 0.f};
  f32x4 acc[4][4];
#pragma unroll
  for (int m = 0; m < 4; ++m)
#pragma unroll
    for (int n = 0; n < 4; ++n) acc[m][n] = zero;

  const int crow = ln >> 3;
  const int ssl = (ln & 7) ^ crow;

  const int klo = sidx * Kc;
  const int khi = klo + Kc;

  for (int kk = klo; kk < khi; kk += 64) {
#pragma unroll
    for (int c = 0; c < 4; ++c) {
      const int ch = wv * 4 + c;
      const int row = ch * 8 + crow;
      __builtin_amdgcn_global_load_lds(
          (const __attribute__((address_space(1))) void*)(A + (size_t)(m0 + row) * K + kk + ssl * 8),
          (__attribute__((address_space(3))) void*)(As + ch * 512), 16, 0, 0);
      __builtin_amdgcn_global_load_lds(
          (const __attribute__((address_space(1))) void*)(BT + (size_t)(n0 + row) * K + kk + ssl * 8),
          (__attribute__((address_space(3))) void*)(Bs + ch * 512), 16, 0, 0);
    }
    __syncthreads();

#pragma unroll
    for (int kb = 0; kb < 2; ++kb) {
      const int sl = ((kb << 2) | khalf) ^ r3;
      bf16x8 af[4], bfr[4];
#pragma unroll
      for (int m = 0; m < 4; ++m)
        af[m] = *(const bf16x8*)(As + (wrow + m * 16 + lrow) * 64 + sl * 8);
#pragma unroll
      for (int n = 0; n < 4; ++n)
        bfr[n] = *(const bf16x8*)(Bs + (wcol + n * 16 + lrow) * 64 + sl * 8);
#pragma unroll
      for (int m = 0; m < 4; ++m)
#pragma unroll
        for (int n = 0; n < 4; ++n)
          acc[m][n] = __builtin_amdgcn_mfma_f32_16x16x32_bf16(af[m], bfr[n], acc[m][n], 0, 0, 0);
    }
    __syncthreads();
  }

  const int rbase = khalf << 2;
  if (EPI == 2) {
#pragma unroll
    for (int n = 0; n < 4; ++n) {
      const size_t col = (size_t)(n0 + wcol + n * 16 + lrow);
#pragma unroll
      for (int m = 0; m < 4; ++m) {
        const size_t row = (size_t)(m0 + wrow + m * 16 + rbase);
        u16x4 pk;
        pk[0] = f2bf(acc[m][n][0]); pk[1] = f2bf(acc[m][n][1]);
        pk[2] = f2bf(acc[m][n][2]); pk[3] = f2bf(acc[m][n][3]);
        *(u16x4*)(CT + col * 8192 + row) = pk;
      }
    }
  } else if (EPI == 3) {
    const size_t pbase = (size_t)sidx * 8192 * ldc;
#pragma unroll
    for (int n = 0; n < 4; ++n) {
      const int col = n0 + wcol + n * 16 + lrow;
#pragma unroll
      for (int m = 0; m < 4; ++m) {
        const size_t row = (size_t)(m0 + wrow + m * 16 + rbase);
#pragma unroll
        for (int j = 0; j < 4; ++j)
          CT[pbase + (row + j) * ldc + col] = f2bf(acc[m][n][j]);
      }
    }
  } else {
#pragma unroll
    for (int n = 0; n < 4; ++n) {
      const int col = n0 + wcol + n * 16 + lrow;
      if (col < nreal) {
#pragma unroll
        for (int m = 0; m < 4; ++m) {
          const size_t row = (size_t)(m0 + wrow + m * 16 + rbase);
          float v0 = acc[m][n][0], v1 = acc[m][n][1];
          float v2 = acc[m][n][2], v3 = acc[m][n][3];
          if (EPI == 0) {
            v0 = fmaxf(v0, 0.f); v1 = fmaxf(v1, 0.f);
            v2 = fmaxf(v2, 0.f); v3 = fmaxf(v3, 0.f);
          }
          C[(row + 0) * ldc + col] = v0;
          C[(row + 1) * ldc + col] = v1;
          C[(row + 2) * ldc + col] = v2;
          C[(row + 3) * ldc + col] = v3;
        }
      }
    }
  }
}

// ---------------- 256x256 8-wave 8-phase kernel (round-5 proven schedule) ----
__device__ __forceinline__ void stage_unit(
    const unsigned short* __restrict__ G, int g0, int Kst, int kk,
    char* lds_tile, int isB, int h, int wv, int ln) {
#pragma unroll
  for (int i = 0; i < 2; ++i) {
    const int c = wv * 2 + i;
    int rb;
    if (isB) rb = ((c >> 2) << 6) + h * 32 + ((c & 3) << 3);
    else     rb = ((c & 8) << 4) + h * 64 + ((c & 7) << 3);
    const int ssl = (ln & 7) ^ (ln >> 3);
    const unsigned short* src = G + (size_t)(g0 + rb + (ln >> 3)) * Kst + kk + ssl * 8;
    __builtin_amdgcn_global_load_lds(
        (const __attribute__((address_space(1))) void*)src,
        (__attribute__((address_space(3))) void*)(lds_tile + rb * 128), 16, 0, 0);
  }
}

#define VM_NONE
#define VM4 asm volatile("s_waitcnt vmcnt(4)" ::: "memory");
#define VM0 asm volatile("s_waitcnt vmcnt(0)" ::: "memory");
#define VMC if (more) { VM4 } else { VM0 }

#define LD_FA(BB, MH)                                                              \
  _Pragma("unroll") for (int kb = 0; kb < 2; ++kb) {                               \
    const int sl = ((kb << 2) | khalf) ^ r3;                                       \
    _Pragma("unroll") for (int fr = 0; fr < 4; ++fr)                               \
      fa[fr][kb] = *(const bf16x8*)((const unsigned short*)(smem + (BB) * 65536)   \
                   + (wmrow + (MH) * 64 + fr * 16 + lrow) * 64 + sl * 8);          \
  }

#define LD_FB(BB, NH, F)                                                           \
  _Pragma("unroll") for (int kb = 0; kb < 2; ++kb) {                               \
    const int sl = ((kb << 2) | khalf) ^ r3;                                       \
    _Pragma("unroll") for (int fc = 0; fc < 2; ++fc)                               \
      F[fc][kb] = *(const bf16x8*)((const unsigned short*)(smem + (BB) * 65536 + 32768) \
                  + (wncol + (NH) * 32 + fc * 16 + lrow) * 64 + sl * 8);           \
  }

#define PH(MH, NH, F, WAITSTMT, DSSTMT, ...)                                       \
  {                                                                                \
    DSSTMT                                                                         \
    __VA_ARGS__;                                                                   \
    __builtin_amdgcn_sched_barrier(0);                                             \
    __builtin_amdgcn_s_barrier();                                                  \
    __builtin_amdgcn_sched_barrier(0);                                             \
    __builtin_amdgcn_s_setprio(1);                                                 \
    _Pragma("unroll") for (int kb = 0; kb < 2; ++kb)                               \
      _Pragma("unroll") for (int fr = 0; fr < 4; ++fr)                             \
        _Pragma("unroll") for (int fc = 0; fc < 2; ++fc)                           \
          acc[MH][NH][fr][fc] = __builtin_amdgcn_mfma_f32_16x16x32_bf16(           \
              fa[fr][kb], F[fc][kb], acc[MH][NH][fr][fc], 0, 0, 0);                \
    __builtin_amdgcn_s_setprio(0);                                                 \
    __builtin_amdgcn_sched_barrier(0);                                             \
    WAITSTMT                                                                       \
    __builtin_amdgcn_s_barrier();                                                  \
    __builtin_amdgcn_sched_barrier(0);                                             \
  }

template<int EPI>
__global__ __launch_bounds__(512, 1)
void k_gemm256(const unsigned short* __restrict__ A, const unsigned short* __restrict__ BT,
               float* __restrict__ C, unsigned short* __restrict__ CT,
               int K, int Kc, int ldc, int nreal) {
  extern __shared__ char smem[];
  const int tid = threadIdx.x;
  const int wv = tid >> 6, ln = tid & 63;
  const int wmrow = (wv >> 2) << 7;
  const int wncol = (wv & 3) << 6;
  const int lrow = ln & 15, khalf = ln >> 4, r3 = ln & 7;

  // XCD-aware bijective swizzle, n-major within each XCD's chunk.
  const int gx = gridDim.x, gy = gridDim.y;
  const int nwg = gx * gy;
  const int bid = blockIdx.y * gx + blockIdx.x;
  const int q8 = nwg >> 3, r8 = nwg & 7;
  const int xcd = bid & 7, lx = bid >> 3;
  const int wgid = (xcd < r8 ? xcd * (q8 + 1) : r8 * (q8 + 1) + (xcd - r8) * q8) + lx;
  const int m0 = (wgid / gy) << 8;
  const int n0 = (wgid % gy) << 8;
  const int klo = blockIdx.z * Kc;
  const int NT = Kc >> 6;
  const int npairs = NT >> 1;

  f32x4 acc[2][2][4][2];
#pragma unroll
  for (int a0 = 0; a0 < 2; ++a0)
#pragma unroll
    for (int a1 = 0; a1 < 2; ++a1)
#pragma unroll
      for (int a2 = 0; a2 < 4; ++a2)
#pragma unroll
        for (int a3 = 0; a3 < 2; ++a3) {
          acc[a0][a1][a2][a3][0] = 0.f; acc[a0][a1][a2][a3][1] = 0.f;
          acc[a0][a1][a2][a3][2] = 0.f; acc[a0][a1][a2][a3][3] = 0.f;
        }

  bf16x8 fa[4][2], fb0[2][2], fb1[2][2];

  stage_unit(A, m0, K, klo, smem, 0, 0, wv, ln);
  stage_unit(BT, n0, K, klo, smem + 32768, 1, 0, wv, ln);
  stage_unit(BT, n0, K, klo, smem + 32768, 1, 1, wv, ln);
  stage_unit(A, m0, K, klo, smem, 0, 1, wv, ln);
  stage_unit(A, m0, K, klo + 64, smem + 65536, 0, 0, wv, ln);
  stage_unit(BT, n0, K, klo + 64, smem + 65536 + 32768, 1, 0, wv, ln);
  VM4
  __builtin_amdgcn_sched_barrier(0);
  __builtin_amdgcn_s_barrier();
  __builtin_amdgcn_sched_barrier(0);

  for (int i = 0; i < npairs; ++i) {
    const int t = i << 1;
    const int kk1 = klo + (t + 1) * 64;
    const int kk2 = klo + (t + 2) * 64;
    const int kk3 = klo + (t + 3) * 64;
    const bool more = (i + 1 < npairs);

    PH(0, 0, fb0, VM_NONE, LD_FA(0, 0) LD_FB(0, 0, fb0),
       stage_unit(A, m0, K, kk1, smem + 65536, 0, 1, wv, ln))
    PH(0, 1, fb1, VM_NONE, LD_FB(0, 1, fb1),
       stage_unit(BT, n0, K, kk1, smem + 65536 + 32768, 1, 1, wv, ln))
    PH(1, 0, fb0, VM_NONE, LD_FA(0, 1),
       if (more) stage_unit(A, m0, K, kk2, smem, 0, 0, wv, ln))
    PH(1, 1, fb1, VMC, ,
       if (more) stage_unit(BT, n0, K, kk2, smem + 32768, 1, 0, wv, ln))
    PH(0, 0, fb0, VM_NONE, LD_FA(1, 0) LD_FB(1, 0, fb0),
       if (more) stage_unit(A, m0, K, kk2, smem, 0, 1, wv, ln))
    PH(0, 1, fb1, VM_NONE, LD_FB(1, 1, fb1),
       if (more) stage_unit(BT, n0, K, kk2, smem + 32768, 1, 1, wv, ln))
    PH(1, 0, fb0, VM_NONE, LD_FA(1, 1),
       if (more) stage_unit(A, m0, K, kk3, smem + 65536, 0, 0, wv, ln))
    PH(1, 1, fb1, if (more) { VM4 }, ,
       if (more) stage_unit(BT, n0, K, kk3, smem + 65536 + 32768, 1, 0, wv, ln))
  }

  const int rb = khalf << 2;
  if (EPI == 2) {
#pragma unroll
    for (int mh = 0; mh < 2; ++mh)
#pragma unroll
      for (int nh = 0; nh < 2; ++nh)
#pragma unroll
        for (int fr = 0; fr < 4; ++fr)
#pragma unroll
          for (int fc = 0; fc < 2; ++fc) {
            const size_t col = (size_t)(n0 + wncol + nh * 32 + fc * 16 + lrow);
            const size_t row = (size_t)(m0 + wmrow + mh * 64 + fr * 16 + rb);
            u16x4 pk;
            pk[0] = f2bf(acc[mh][nh][fr][fc][0]); pk[1] = f2bf(acc[mh][nh][fr][fc][1]);
            pk[2] = f2bf(acc[mh][nh][fr][fc][2]); pk[3] = f2bf(acc[mh][nh][fr][fc][3]);
            *(u16x4*)(CT + col * 8192 + row) = pk;
          }
  } else if (EPI == 3) {
    const size_t pbase = (size_t)blockIdx.z * 8192 * ldc;
#pragma unroll
    for (int mh = 0; mh < 2; ++mh)
#pragma unroll
      for (int nh = 0; nh < 2; ++nh)
#pragma unroll
        for (int fr = 0; fr < 4; ++fr)
#pragma unroll
          for (int fc = 0; fc < 2; ++fc) {
            const int col = n0 + wncol + nh * 32 + fc * 16 + lrow;
            const size_t row = (size_t)(m0 + wmrow + mh * 64 + fr * 16 + rb);
#pragma unroll
            for (int j = 0; j < 4; ++j)
              CT[pbase + (row + j) * ldc + col] = f2bf(acc[mh][nh][fr][fc][j]);
          }
  } else {
#pragma unroll
    for (int mh = 0; mh < 2; ++mh)
#pragma unroll
      for (int nh = 0; nh < 2; ++nh)
#pragma unroll
        for (int fc = 0; fc < 2; ++fc) {
          const int col = n0 + wncol + nh * 32 + fc * 16 + lrow;
          if (col < nreal) {
#pragma unroll
            for (int fr = 0; fr < 4; ++fr) {
              const size_t row = (size_t)(m0 + wmrow + mh * 64 + fr * 16 + rb);
#pragma unroll
              for (int j = 0; j < 4; ++j) {
                float v = acc[mh][nh][fr][fc][j];
                if (EPI == 0) v = fmaxf(v, 0.f);
                C[(row + j) * ldc + col] = v;
              }
            }
          }
        }
  }
}

extern "C" void kernel_launch(void* const* d_in, const int* in_sizes, int n_in,
                              void* d_out, int out_size, void* d_ws, size_t ws_size,
                              hipStream_t stream) {
  (void)in_sizes; (void)n_in; (void)out_size;
  const float* x    = (const float*)d_in[0];
  const float* adj  = (const float*)d_in[1];
  const float* adjx = (const float*)d_in[2];
  const float* tra1 = (const float*)d_in[3];
  const float* tra2 = (const float*)d_in[4];
  const float* tra3 = (const float*)d_in[5];
  const float* h    = (const float*)d_in[6];
  const float* W1   = (const float*)d_in[7];
  const float* W2   = (const float*)d_in[8];
  const float* W3   = (const float*)d_in[9];
  const float* W4   = (const float*)d_in[10];
  const float* W5   = (const float*)d_in[11];
  float* out = (float*)d_out;

  const size_t ADJ_B  = 134217728;
  const size_t FEAT_B = 33554432;
  const size_t SUP_B  = 33554432;
  const size_t W_B    = 2097152;
  if (ws_size < ADJ_B + FEAT_B + SUP_B + W_B) return;
  const bool twoadj = ws_size >= 2 * ADJ_B + FEAT_B + SUP_B + W_B;
  char* ws = (char*)d_ws;
  unsigned short* adjB = (unsigned short*)ws;
  unsigned short* adjW;   // blended adjacency (layers 2-5)
  unsigned short *featB, *supB, *wB;
  if (twoadj) {
    adjW  = (unsigned short*)(ws + ADJ_B);
    featB = (unsigned short*)(ws + 2 * ADJ_B);
    supB  = (unsigned short*)(ws + 2 * ADJ_B + FEAT_B);
    wB    = (unsigned short*)(ws + 2 * ADJ_B + FEAT_B + SUP_B);
  } else {
    adjW  = adjB;
    featB = (unsigned short*)(ws + ADJ_B);
    supB  = (unsigned short*)(ws + ADJ_B + FEAT_B);
    wB    = (unsigned short*)(ws + ADJ_B + FEAT_B + SUP_B);
  }
  unsigned short* partB = featB;

  float* z5 = out;
  float* z1 = out + 81920;
  float* z2 = out + 4177920;
  float* z3 = out + 8273920;
  float* z4 = out + 24657920;

  const long n4adj = (long)8192 * 8192 / 4;
  const int SMEM = 131072;

  bool big = true;
  if (hipFuncSetAttribute(reinterpret_cast<const void*>(&k_gemm256<0>),
                          hipFuncAttributeMaxDynamicSharedMemorySize, SMEM) != hipSuccess) big = false;
  if (hipFuncSetAttribute(reinterpret_cast<const void*>(&k_gemm256<2>),
                          hipFuncAttributeMaxDynamicSharedMemorySize, SMEM) != hipSuccess) big = false;
  if (hipFuncSetAttribute(reinterpret_cast<const void*>(&k_gemm256<3>),
                          hipFuncAttributeMaxDynamicSharedMemorySize, SMEM) != hipSuccess) big = false;

  // ---- layer 1: z1 = relu(adj @ (x @ W1)) ----
  if (twoadj)
    k_cvt2<<<2048, 256, 0, stream>>>(adj, adjx, adjB, adjW, n4adj);
  else
    k_cvtblend<<<2048, 256, 0, stream>>>(adj, nullptr, adjB, n4adj);
  k_feat<<<2048, 256, 0, stream>>>(x, nullptr, featB, 1000, 10, (long)8192 * 1024, 1.f, 0.f);
  k_wt<<<512, 256, 0, stream>>>(W1, wB, 1000, 500, 10, (long)512 * 1024);
  k_gemm<2><<<dim3(64, 4, 1), 256, 0, stream>>>(featB, wB, nullptr, supB, 1024, 1024, 0, 0);
  if (big)
    k_gemm256<3><<<dim3(32, 2, 4), 512, SMEM, stream>>>(adjB, supB, nullptr, partB, 8192, 2048, 512, 0);
  else
    k_gemm<3><<<dim3(64, 4, 4), 256, 0, stream>>>(adjB, supB, nullptr, partB, 8192, 2048, 512, 0);
  // fused: z1 + feat2 (feat2 overwrites part slice-0 region, alias-safe)
  k_reduce_f<<<2048, 256, 0, stream>>>(partB, z1, tra1, featB, 4, 512, 7, 500, (long)8192 * 128);

  if (!twoadj)
    k_blend2<<<2048, 256, 0, stream>>>(adjB, adjx, n4adj);

  // ---- layer 2: z2 = relu(adj_b @ (feat2 @ W2)) ----
  k_wt<<<512, 256, 0, stream>>>(W2, wB, 500, 500, 9, (long)512 * 512);
  k_gemm<2><<<dim3(64, 4, 1), 256, 0, stream>>>(featB, wB, nullptr, supB, 512, 512, 0, 0);
  if (big)
    k_gemm256<3><<<dim3(32, 2, 4), 512, SMEM, stream>>>(adjW, supB, nullptr, partB, 8192, 2048, 512, 0);
  else
    k_gemm<3><<<dim3(64, 4, 4), 256, 0, stream>>>(adjW, supB, nullptr, partB, 8192, 2048, 512, 0);
  // fused: z2 + feat3 (row-major [8192][512])
  k_reduce_f<<<2048, 256, 0, stream>>>(partB, z2, tra2, featB, 4, 512, 7, 500, (long)8192 * 128);

  // ---- layer 3, REASSOCIATED: z3 = relu((adj_b @ feat3) @ W3) ----
  // T = adj_b @ feat3 costs 68.7 GF (vs 275 GF for adj_b @ (feat3@W3)).
  // 1. transpose feat3 -> feat3T [512][8192] (BT operand layout)
  k_tr<<<dim3(128, 8), 256, 0, stream>>>(featB, supB, 8192, 512);
  k_wt<<<512, 256, 0, stream>>>(W3, wB, 500, 2000, 9, (long)2048 * 512);
  // 2. split-K adjacency GEMM: partials [4][8192][512] -> featB (feat3 row-major dead)
  if (big) {
    k_gemm256<3><<<dim3(32, 2, 4), 512, SMEM, stream>>>(adjW, supB, nullptr, partB, 8192, 2048, 512, 0);
  } else {
    k_gemm<3><<<dim3(64, 4, 4), 256, 0, stream>>>(adjW, supB, nullptr, partB, 8192, 2048, 512, 0);
  }
  // 3. reduce partials -> T bf16 [8192][512] (slice-0 alias, NO relu)
  k_reduce_b<<<2048, 256, 0, stream>>>(partB, featB, 4, (long)8192 * 512, (long)8192 * 128);
  // 4. z3 = relu(T @ W3): A = T (K=512), BT = wB
  if (big)
    k_gemm256<0><<<dim3(32, 8, 1), 512, SMEM, stream>>>(featB, wB, z3, nullptr, 512, 512, 2000, 2000);
  else
    k_gemm<0><<<dim3(64, 16, 1), 256, 0, stream>>>(featB, wB, z3, nullptr, 512, 512, 2000, 2000);
  // 5. feat4 = 0.5*z3 + 0.5*tra3 (overwrites T)
  k_feat<<<2048, 256, 0, stream>>>(z3, tra3, featB, 2000, 11, (long)8192 * 2048, 0.5f, 0.5f);

  // ---- layer 4 (split-K path) ----
  k_wt<<<512, 256, 0, stream>>>(W4, wB, 2000, 10, 11, (long)128 * 2048);
  k_gemm<2><<<dim3(64, 1, 1), 256, 0, stream>>>(featB, wB, nullptr, supB, 2048, 2048, 0, 0);
  k_gemm<3><<<dim3(64, 1, 8), 256, 0, stream>>>(adjW, supB, nullptr, partB, 8192, 1024, 128, 0);
  k_reduce<<<2048, 256, 0, stream>>>(partB, z4, 8, 128, 5, 10, 1, (long)8192 * 32);

  // ---- layer 5 (no relu) ----
  k_feat<<<512, 256, 0, stream>>>(z4, h, featB, 10, 6, (long)8192 * 64, 0.5f, 0.5f);
  k_wt<<<64, 256, 0, stream>>>(W5, wB, 10, 10, 6, (long)128 * 64);
  k_gemm<2><<<dim3(64, 1, 1), 256, 0, stream>>>(featB, wB, nullptr, supB, 64, 64, 0, 0);
  k_gemm<3><<<dim3(64, 1, 8), 256, 0, stream>>>(adjW, supB, nullptr, partB, 8192, 1024, 128, 0);
  k_reduce<<<2048, 256, 0, stream>>>(partB, z5, 8, 128, 5, 10, 0, (long)8192 * 32);
}